// Round 5
// baseline (1089.296 us; speedup 1.0000x reference)
//
#include <hip/hip_runtime.h>
#include <hip/hip_fp16.h>
#include <hip/hip_cooperative_groups.h>

// SparseConvolutionDownsample: rulebook sparse conv (gather -> GEMM -> scatter-add)
// + BatchNorm over active sites + LeakyReLU(0.333).
//
// Constants: C_IN=64, C_OUT=128, K=4, P=262144, n_out=262144.
//
// R8: ONE cooperative kernel for the whole pipeline (fill+Wt / conv / stats /
// reduce / apply with grid.sync between phases). R7 falsified the SDMA-memset
// theory (memset==fill cost); ~270us of aux time is unexplained by traffic
// and constant across all aux restructurings -> per-dispatch overhead theory.
// This collapses 5 dispatches to 1. Conv phase itself is unchanged (at the
// ~274 Gops/s pk-f16 atomic ceiling, 248us).
// Fallbacks: R7 multi-kernel path if cooperative launch unavailable/fails;
// R2 fp32 path if ws tiny.

namespace cg = cooperative_groups;

#define C_IN   64
#define C_OUT  128
#define KOFF   4
#define TILE_P 128
#define SF_LD  72            // bf16 elems/row: 144B stride (16B-aligned)
#define BN_EPS 1e-4f
#define LEAK   0.333f
#define STATS_BLOCKS 2048    // stage-1 grid for partial stats (fallback path)
#define FILL_BLOCKS  4096    // zero-fill grid (fallback path)

typedef __attribute__((ext_vector_type(8)))  short short8;
typedef __attribute__((ext_vector_type(4)))  float f32x4;
typedef __attribute__((ext_vector_type(16))) float f32x16;

__device__ inline unsigned short f32_to_bf16_rn(float x) {
    unsigned int b = __float_as_uint(x);
    unsigned int r = (b + 0x7FFFu + ((b >> 16) & 1u)) >> 16;
    return (unsigned short)r;
}

struct h2pair { __half2 a, b; };   // 8 B = 4 channels

// ===========================================================================
// R8 fused cooperative pipeline.
// Phases: 0) zero accumulator + build Wt   1) conv (MFMA + pk_f16 scatter)
//         2) per-block partial stats       3) 8-block reduce -> partial2
//         4) BN apply + LeakyReLU
// LDS is a union across phases (18.9 KB) -> 8 blocks/CU co-resident.
// ===========================================================================
__global__ __launch_bounds__(256, 8) void fused_pipeline_kernel(
    const float* __restrict__ feats, const float* __restrict__ W,
    const int* __restrict__ in_idx, const int* __restrict__ out_idx,
    const float* __restrict__ gamma, const float* __restrict__ beta,
    __half2* __restrict__ outh, unsigned short* __restrict__ Wt,
    float* __restrict__ partial, float* __restrict__ partial2,
    float* __restrict__ outp, int P, int n_out)
{
    __shared__ union SMem {
        struct { unsigned short sF[TILE_P][SF_LD]; int sO[TILE_P]; } conv; // 18944 B
        struct { float4 red[256]; float4 red2[256]; } st;                  // 8192 B
        float sStats[2 * C_OUT];                                           // 1024 B
    } sm;

    cg::grid_group grid = cg::this_grid();
    const int tid = threadIdx.x;
    const int bid = blockIdx.x;
    const int G   = gridDim.x;

    // ---------------- Phase 0: zero accumulator; first KOFF blocks build Wt.
    {
        uint4* fill = (uint4*)outh;
        const size_t fill_u4 = ((size_t)n_out * C_OUT * 2) / 16;
        const uint4 z = make_uint4(0u, 0u, 0u, 0u);
        for (size_t i = (size_t)bid * 256 + tid; i < fill_u4; i += (size_t)G * 256)
            fill[i] = z;

        if (bid < KOFF) {
            const int k = bid;
            const int n  = tid >> 1;
            const int c0 = (tid & 1) * 32;
            unsigned int buf[16];
            #pragma unroll
            for (int j = 0; j < 16; ++j) {
                int cc = c0 + 2 * j;
                unsigned short lo = f32_to_bf16_rn(W[((size_t)k * C_IN + cc) * C_OUT + n]);
                unsigned short hh = f32_to_bf16_rn(W[((size_t)k * C_IN + cc + 1) * C_OUT + n]);
                buf[j] = (unsigned int)lo | ((unsigned int)hh << 16);
            }
            uint4* dst = (uint4*)(Wt + ((size_t)k * C_OUT + n) * C_IN + c0);
            dst[0] = make_uint4(buf[0],  buf[1],  buf[2],  buf[3]);
            dst[1] = make_uint4(buf[4],  buf[5],  buf[6],  buf[7]);
            dst[2] = make_uint4(buf[8],  buf[9],  buf[10], buf[11]);
            dst[3] = make_uint4(buf[12], buf[13], buf[14], buf[15]);
        }
    }
    grid.sync();

    // ---------------- Phase 1: conv (grid-stride over virtual tiles).
    {
        const int ntp = P / TILE_P;
        const int nvt = KOFF * ntp;
        const int l  = tid & 63;
        const int w  = tid >> 6;        // wave id -> col base 32w
        const int c  = l & 31;          // A row / B col / D col
        const int hi = l >> 5;          // k-half selector; D row +4*hi
        const bool odd = (c & 1) != 0;
        const int cpair = 16 * w + (c >> 1);

        for (int vt = bid; vt < nvt; vt += G) {
            const int k  = vt / ntp;
            const int p0 = (vt - k * ntp) * TILE_P;

            __syncthreads();   // protect LDS reuse across vt iterations
            if (tid < TILE_P)
                sm.conv.sO[tid] = out_idx[(size_t)k * P + p0 + tid];
            for (int i = tid; i < TILE_P * (C_IN / 4); i += 256) {
                int r  = i >> 4;
                int c4 = i & 15;
                int src = in_idx[(size_t)k * P + p0 + r];
                float4 v = ((const float4*)(feats + (size_t)src * C_IN))[c4];
                unsigned int lo = (unsigned int)f32_to_bf16_rn(v.x) | ((unsigned int)f32_to_bf16_rn(v.y) << 16);
                unsigned int hu = (unsigned int)f32_to_bf16_rn(v.z) | ((unsigned int)f32_to_bf16_rn(v.w) << 16);
                *(uint2*)&sm.conv.sF[r][c4 * 4] = make_uint2(lo, hu);
            }

            short8 bfr[4];
            {
                const unsigned short* wb = Wt + ((size_t)(k * C_OUT + 32 * w + c)) * C_IN + 8 * hi;
                #pragma unroll
                for (int s = 0; s < 4; ++s)
                    bfr[s] = *(const short8*)(wb + 16 * s);
            }
            __syncthreads();

            #pragma unroll
            for (int m = 0; m < 4; ++m) {
                f32x16 acc;
                #pragma unroll
                for (int j = 0; j < 16; ++j) acc[j] = 0.f;

                #pragma unroll
                for (int s = 0; s < 4; ++s) {
                    short8 a = *(const short8*)&sm.conv.sF[32 * m + c][16 * s + 8 * hi];
                    acc = __builtin_amdgcn_mfma_f32_32x32x16_bf16(a, bfr[s], acc, 0, 0, 0);
                }

                // Pair regs (e,e+1) -> rows (R,R+1); shfl_xor(1) pairs
                // adjacent-lane cols -> 4 distinct rows x full 64B per atomic.
                #pragma unroll
                for (int e = 0; e < 16; e += 2) {
                    const int rbase = 32 * m + (e & 3) + 8 * (e >> 2) + 4 * hi;
                    float va = acc[e], vb = acc[e + 1];
                    float ta = __shfl_xor(va, 1);
                    float tb = __shfl_xor(vb, 1);
                    int row = sm.conv.sO[rbase + (odd ? 1 : 0)];
                    __half2 h = odd ? __floats2half2_rn(tb, vb) : __floats2half2_rn(va, ta);
                    unsafeAtomicAdd(outh + (size_t)row * (C_OUT / 2) + cpair, h);
                }
            }
        }
    }
    grid.sync();

    // ---------------- Phase 2: per-block partial sum/sumsq (no atomics).
    {
        const int c4   = tid & 31;
        const int rgrp = tid >> 5;
        float4 s  = make_float4(0.f, 0.f, 0.f, 0.f);
        float4 s2 = make_float4(0.f, 0.f, 0.f, 0.f);
        for (int r = bid * 8 + rgrp; r < n_out; r += G * 8) {
            h2pair u = ((const h2pair*)(outh + (size_t)r * (C_OUT / 2)))[c4];
            float2 fa = __half22float2(u.a), fb = __half22float2(u.b);
            s.x += fa.x; s.y += fa.y; s.z += fb.x; s.w += fb.y;
            s2.x += fa.x * fa.x; s2.y += fa.y * fa.y; s2.z += fb.x * fb.x; s2.w += fb.y * fb.y;
        }
        sm.st.red[tid] = s; sm.st.red2[tid] = s2;
        __syncthreads();
        if (tid < 32) {
            #pragma unroll
            for (int j = 1; j < 8; ++j) {
                float4 a = sm.st.red[tid + 32 * j], b = sm.st.red2[tid + 32 * j];
                s.x += a.x; s.y += a.y; s.z += a.z; s.w += a.w;
                s2.x += b.x; s2.y += b.y; s2.z += b.z; s2.w += b.w;
            }
            float* pb = partial + (size_t)bid * 2 * C_OUT;
            ((float4*)pb)[tid] = s;
            ((float4*)(pb + C_OUT))[tid] = s2;
        }
    }
    grid.sync();

    // ---------------- Phase 3: reduce G partials -> partial2[8][256].
    if (bid < 8) {
        const int chunk = (G + 7) >> 3;
        const int b0 = bid * chunk;
        int b1 = b0 + chunk; if (b1 > G) b1 = G;
        float a = 0.f;
        for (int b = b0; b < b1; ++b)
            a += partial[(size_t)b * 2 * C_OUT + tid];
        partial2[(size_t)bid * 2 * C_OUT + tid] = a;
    }
    grid.sync();

    // ---------------- Phase 4: BN apply + LeakyReLU.
    {
        float a = 0.f;
        #pragma unroll
        for (int j = 0; j < 8; ++j)
            a += partial2[(size_t)j * 2 * C_OUT + tid];
        sm.sStats[tid] = a;
        __syncthreads();

        const float inv_n = 1.0f / (float)n_out;
        const size_t total = (size_t)n_out * (C_OUT / 4);
        size_t i = (size_t)bid * 256 + tid;
        const int c = (int)(tid & 31) * 4;

        float4 sc, sh;
        {
            float m0 = sm.sStats[c + 0] * inv_n, m1 = sm.sStats[c + 1] * inv_n,
                  m2 = sm.sStats[c + 2] * inv_n, m3 = sm.sStats[c + 3] * inv_n;
            float v0 = sm.sStats[C_OUT + c + 0] * inv_n - m0 * m0;
            float v1 = sm.sStats[C_OUT + c + 1] * inv_n - m1 * m1;
            float v2 = sm.sStats[C_OUT + c + 2] * inv_n - m2 * m2;
            float v3 = sm.sStats[C_OUT + c + 3] * inv_n - m3 * m3;
            sc.x = gamma[c + 0] * rsqrtf(v0 + BN_EPS);
            sc.y = gamma[c + 1] * rsqrtf(v1 + BN_EPS);
            sc.z = gamma[c + 2] * rsqrtf(v2 + BN_EPS);
            sc.w = gamma[c + 3] * rsqrtf(v3 + BN_EPS);
            sh.x = beta[c + 0] - m0 * sc.x;
            sh.y = beta[c + 1] - m1 * sc.y;
            sh.z = beta[c + 2] - m2 * sc.z;
            sh.w = beta[c + 3] - m3 * sc.w;
        }

        const h2pair* ih = (const h2pair*)outh;
        float4* o4 = (float4*)outp;
        for (; i < total; i += (size_t)G * 256) {
            h2pair u = ih[i];
            float2 fa = __half22float2(u.a), fb = __half22float2(u.b);
            float4 v = make_float4(fa.x, fa.y, fb.x, fb.y);
            v.x = v.x * sc.x + sh.x; v.x = v.x >= 0.f ? v.x : LEAK * v.x;
            v.y = v.y * sc.y + sh.y; v.y = v.y >= 0.f ? v.y : LEAK * v.y;
            v.z = v.z * sc.z + sh.z; v.z = v.z >= 0.f ? v.z : LEAK * v.z;
            v.w = v.w * sc.w + sh.w; v.w = v.w >= 0.f ? v.w : LEAK * v.w;
            o4[i] = v;
        }
    }
}

// ===========================================================================
// R7 MULTI-KERNEL FALLBACK PATH (unchanged)
// ===========================================================================

__global__ __launch_bounds__(256) void fill_wt_kernel(
    const float* __restrict__ W, unsigned short* __restrict__ Wt,
    uint4* __restrict__ fill, size_t fill_u4)
{
    const int bid = blockIdx.x;
    if (bid < FILL_BLOCKS) {
        const uint4 z = make_uint4(0u, 0u, 0u, 0u);
        size_t i = (size_t)bid * 256 + threadIdx.x;
        const size_t stride = (size_t)FILL_BLOCKS * 256;
        for (; i < fill_u4; i += stride)
            fill[i] = z;
        return;
    }

    const int k = bid - FILL_BLOCKS;
    const int t = threadIdx.x;
    const int n  = t >> 1;
    const int c0 = (t & 1) * 32;

    unsigned int buf[16];
    #pragma unroll
    for (int j = 0; j < 16; ++j) {
        int c = c0 + 2 * j;
        unsigned short lo = f32_to_bf16_rn(W[((size_t)k * C_IN + c) * C_OUT + n]);
        unsigned short hi = f32_to_bf16_rn(W[((size_t)k * C_IN + c + 1) * C_OUT + n]);
        buf[j] = (unsigned int)lo | ((unsigned int)hi << 16);
    }
    uint4* dst = (uint4*)(Wt + ((size_t)k * C_OUT + n) * C_IN + c0);
    dst[0] = make_uint4(buf[0],  buf[1],  buf[2],  buf[3]);
    dst[1] = make_uint4(buf[4],  buf[5],  buf[6],  buf[7]);
    dst[2] = make_uint4(buf[8],  buf[9],  buf[10], buf[11]);
    dst[3] = make_uint4(buf[12], buf[13], buf[14], buf[15]);
}

__global__ __launch_bounds__(256) void scatter_gemm_mfma_kernel(
    const float* __restrict__ feats, const unsigned short* __restrict__ Wt,
    const int* __restrict__ in_idx, const int* __restrict__ out_idx,
    __half2* __restrict__ outh, int P)
{
    __shared__ unsigned short sF[TILE_P][SF_LD];
    __shared__ int sO[TILE_P];

    const int tid = threadIdx.x;
    const int k  = blockIdx.y;
    const int p0 = blockIdx.x * TILE_P;

    if (tid < TILE_P)
        sO[tid] = out_idx[(size_t)k * P + p0 + tid];

    for (int i = tid; i < TILE_P * (C_IN / 4); i += 256) {
        int r  = i >> 4;
        int c4 = i & 15;
        int src = in_idx[(size_t)k * P + p0 + r];
        float4 v = ((const float4*)(feats + (size_t)src * C_IN))[c4];
        unsigned int lo = (unsigned int)f32_to_bf16_rn(v.x) | ((unsigned int)f32_to_bf16_rn(v.y) << 16);
        unsigned int hi = (unsigned int)f32_to_bf16_rn(v.z) | ((unsigned int)f32_to_bf16_rn(v.w) << 16);
        *(uint2*)&sF[r][c4 * 4] = make_uint2(lo, hi);
    }

    const int l  = tid & 63;
    const int w  = tid >> 6;
    const int c  = l & 31;
    const int hi = l >> 5;
    const bool odd = (c & 1) != 0;
    const int cpair = 16 * w + (c >> 1);

    short8 bfr[4];
    {
        const unsigned short* wb = Wt + ((size_t)(k * C_OUT + 32 * w + c)) * C_IN + 8 * hi;
        #pragma unroll
        for (int s = 0; s < 4; ++s)
            bfr[s] = *(const short8*)(wb + 16 * s);
    }

    __syncthreads();

    #pragma unroll
    for (int m = 0; m < 4; ++m) {
        f32x16 acc;
        #pragma unroll
        for (int j = 0; j < 16; ++j) acc[j] = 0.f;

        #pragma unroll
        for (int s = 0; s < 4; ++s) {
            short8 a = *(const short8*)&sF[32 * m + c][16 * s + 8 * hi];
            acc = __builtin_amdgcn_mfma_f32_32x32x16_bf16(a, bfr[s], acc, 0, 0, 0);
        }

        #pragma unroll
        for (int e = 0; e < 16; e += 2) {
            const int rbase = 32 * m + (e & 3) + 8 * (e >> 2) + 4 * hi;
            float va = acc[e], vb = acc[e + 1];
            float ta = __shfl_xor(va, 1);
            float tb = __shfl_xor(vb, 1);
            int row = sO[rbase + (odd ? 1 : 0)];
            __half2 h = odd ? __floats2half2_rn(tb, vb) : __floats2half2_rn(va, ta);
            unsafeAtomicAdd(outh + (size_t)row * (C_OUT / 2) + cpair, h);
        }
    }
}

__global__ __launch_bounds__(256) void bn_stats_partial_kernel(
    const __half2* __restrict__ outh, float* __restrict__ partial, int n_out)
{
    const int tid = threadIdx.x;
    const int c4   = tid & 31;
    const int rgrp = tid >> 5;

    float4 s  = make_float4(0.f, 0.f, 0.f, 0.f);
    float4 s2 = make_float4(0.f, 0.f, 0.f, 0.f);
    for (int r = blockIdx.x * 8 + rgrp; r < n_out; r += gridDim.x * 8) {
        h2pair u = ((const h2pair*)(outh + (size_t)r * (C_OUT / 2)))[c4];
        float2 fa = __half22float2(u.a), fb = __half22float2(u.b);
        s.x += fa.x; s.y += fa.y; s.z += fb.x; s.w += fb.y;
        s2.x += fa.x * fa.x; s2.y += fa.y * fa.y; s2.z += fb.x * fb.x; s2.w += fb.y * fb.y;
    }

    __shared__ float4 red[256], red2[256];
    red[tid] = s; red2[tid] = s2;
    __syncthreads();
    if (tid < 32) {
        #pragma unroll
        for (int j = 1; j < 8; ++j) {
            float4 a = red[tid + 32 * j], b = red2[tid + 32 * j];
            s.x += a.x; s.y += a.y; s.z += a.z; s.w += a.w;
            s2.x += b.x; s2.y += b.y; s2.z += b.z; s2.w += b.w;
        }
        float* pb = partial + (size_t)blockIdx.x * 2 * C_OUT;
        ((float4*)pb)[tid] = s;
        ((float4*)(pb + C_OUT))[tid] = s2;
    }
}

__global__ __launch_bounds__(256) void bn_reduce_kernel(
    const float* __restrict__ partial, float* __restrict__ stats)
{
    const int tid = threadIdx.x;
    const int b0 = blockIdx.x * (STATS_BLOCKS / 8);
    float a = 0.f;
    for (int b = b0; b < b0 + STATS_BLOCKS / 8; ++b)
        a += partial[(size_t)b * 2 * C_OUT + tid];
    atomicAdd(&stats[tid], a);
}

__global__ __launch_bounds__(256) void bn_apply_half_kernel(
    const __half2* __restrict__ outh, float* __restrict__ out,
    const float* __restrict__ stats,
    const float* __restrict__ gamma, const float* __restrict__ beta,
    int n_out, float inv_n)
{
    const size_t total = (size_t)n_out * (C_OUT / 4);
    size_t i = (size_t)blockIdx.x * 256 + threadIdx.x;
    const int c = (int)(i & 31) * 4;

    float4 sc, sh;
    {
        float m0 = stats[c + 0] * inv_n, m1 = stats[c + 1] * inv_n,
              m2 = stats[c + 2] * inv_n, m3 = stats[c + 3] * inv_n;
        float v0 = stats[C_OUT + c + 0] * inv_n - m0 * m0;
        float v1 = stats[C_OUT + c + 1] * inv_n - m1 * m1;
        float v2 = stats[C_OUT + c + 2] * inv_n - m2 * m2;
        float v3 = stats[C_OUT + c + 3] * inv_n - m3 * m3;
        sc.x = gamma[c + 0] * rsqrtf(v0 + BN_EPS);
        sc.y = gamma[c + 1] * rsqrtf(v1 + BN_EPS);
        sc.z = gamma[c + 2] * rsqrtf(v2 + BN_EPS);
        sc.w = gamma[c + 3] * rsqrtf(v3 + BN_EPS);
        sh.x = beta[c + 0] - m0 * sc.x;
        sh.y = beta[c + 1] - m1 * sc.y;
        sh.z = beta[c + 2] - m2 * sc.z;
        sh.w = beta[c + 3] - m3 * sc.w;
    }

    const h2pair* ih = (const h2pair*)outh;
    float4* o4 = (float4*)out;
    for (; i < total; i += (size_t)gridDim.x * 256) {
        h2pair u = ih[i];
        float2 fa = __half22float2(u.a), fb = __half22float2(u.b);
        float4 v = make_float4(fa.x, fa.y, fb.x, fb.y);
        v.x = v.x * sc.x + sh.x; v.x = v.x >= 0.f ? v.x : LEAK * v.x;
        v.y = v.y * sc.y + sh.y; v.y = v.y >= 0.f ? v.y : LEAK * v.y;
        v.z = v.z * sc.z + sh.z; v.z = v.z >= 0.f ? v.z : LEAK * v.z;
        v.w = v.w * sc.w + sh.w; v.w = v.w >= 0.f ? v.w : LEAK * v.w;
        o4[i] = v;
    }
}

// ===========================================================================
// FP32 FALLBACK PATH (R2, unchanged) — used if ws_size too small
// ===========================================================================

__global__ __launch_bounds__(256) void scatter_gemm_f32_kernel(
    const float* __restrict__ feats, const float* __restrict__ W,
    const int* __restrict__ in_idx, const int* __restrict__ out_idx,
    float* __restrict__ out, int P)
{
    __shared__ float sW[C_IN][C_OUT];
    __shared__ unsigned short sF[TILE_P][66];

    const int tid = threadIdx.x;
    const int k  = blockIdx.y;
    const int p0 = blockIdx.x * TILE_P;

    const float4* Wk4 = (const float4*)(W + (size_t)k * C_IN * C_OUT);
    float4* sW4 = (float4*)&sW[0][0];
    #pragma unroll
    for (int i = tid; i < C_IN * C_OUT / 4; i += 256)
        sW4[i] = Wk4[i];

    for (int i = tid; i < TILE_P * (C_IN / 4); i += 256) {
        int r  = i >> 4;
        int c4 = i & 15;
        int src = in_idx[(size_t)k * P + p0 + r];
        float4 v = ((const float4*)(feats + (size_t)src * C_IN))[c4];
        unsigned int lo = (unsigned int)f32_to_bf16_rn(v.x) | ((unsigned int)f32_to_bf16_rn(v.y) << 16);
        unsigned int hi = (unsigned int)f32_to_bf16_rn(v.z) | ((unsigned int)f32_to_bf16_rn(v.w) << 16);
        unsigned int* dst = (unsigned int*)&sF[r][c4 * 4];
        dst[0] = lo;
        dst[1] = hi;
    }
    __syncthreads();

    const int tx = tid & 15;
    const int ty = tid >> 4;

    float acc[8][8];
    #pragma unroll
    for (int r = 0; r < 8; ++r)
        #pragma unroll
        for (int j = 0; j < 8; ++j) acc[r][j] = 0.f;

    #pragma unroll 4
    for (int kk2 = 0; kk2 < C_IN / 2; ++kk2) {
        float w0[8], w1[8];
        #pragma unroll
        for (int j = 0; j < 8; ++j) {
            w0[j] = sW[2 * kk2 + 0][tx + 16 * j];
            w1[j] = sW[2 * kk2 + 1][tx + 16 * j];
        }
        float f0[8], f1[8];
        #pragma unroll
        for (int r = 0; r < 8; ++r) {
            unsigned int u = *(const unsigned int*)&sF[8 * ty + r][2 * kk2];
            f0[r] = __uint_as_float(u << 16);
            f1[r] = __uint_as_float(u & 0xFFFF0000u);
        }
        #pragma unroll
        for (int r = 0; r < 8; ++r)
            #pragma unroll
            for (int j = 0; j < 8; ++j) {
                acc[r][j] = fmaf(f0[r], w0[j], acc[r][j]);
                acc[r][j] = fmaf(f1[r], w1[j], acc[r][j]);
            }
    }

    #pragma unroll
    for (int r = 0; r < 8; ++r) {
        int orow = out_idx[(size_t)k * P + p0 + 8 * ty + r];
        float* op = out + (size_t)orow * C_OUT + tx;
        #pragma unroll
        for (int j = 0; j < 8; ++j)
            atomicAdd(op + 16 * j, acc[r][j]);
    }
}

__global__ __launch_bounds__(256) void bn_stats_f32_kernel(
    const float* __restrict__ out, float* __restrict__ stats, int n_out)
{
    const int tid = threadIdx.x;
    const int c4   = tid & 31;
    const int rgrp = tid >> 5;

    float4 s  = make_float4(0.f, 0.f, 0.f, 0.f);
    float4 s2 = make_float4(0.f, 0.f, 0.f, 0.f);
    for (int r = blockIdx.x * 8 + rgrp; r < n_out; r += gridDim.x * 8) {
        float4 v = ((const float4*)(out + (size_t)r * C_OUT))[c4];
        s.x += v.x; s.y += v.y; s.z += v.z; s.w += v.w;
        s2.x += v.x * v.x; s2.y += v.y * v.y; s2.z += v.z * v.z; s2.w += v.w * v.w;
    }

    __shared__ float4 red[256], red2[256];
    red[tid] = s; red2[tid] = s2;
    __syncthreads();
    if (tid < 32) {
        #pragma unroll
        for (int j = 1; j < 8; ++j) {
            float4 a = red[tid + 32 * j], b = red2[tid + 32 * j];
            s.x += a.x; s.y += a.y; s.z += a.z; s.w += a.w;
            s2.x += b.x; s2.y += b.y; s2.z += b.z; s2.w += b.w;
        }
        atomicAdd(&stats[4 * tid + 0], s.x);
        atomicAdd(&stats[4 * tid + 1], s.y);
        atomicAdd(&stats[4 * tid + 2], s.z);
        atomicAdd(&stats[4 * tid + 3], s.w);
        atomicAdd(&stats[C_OUT + 4 * tid + 0], s2.x);
        atomicAdd(&stats[C_OUT + 4 * tid + 1], s2.y);
        atomicAdd(&stats[C_OUT + 4 * tid + 2], s2.z);
        atomicAdd(&stats[C_OUT + 4 * tid + 3], s2.w);
    }
}

__global__ __launch_bounds__(256) void bn_apply_f32_kernel(
    float* __restrict__ out, const float* __restrict__ stats,
    const float* __restrict__ gamma, const float* __restrict__ beta,
    int n_out, float inv_n)
{
    const size_t total = (size_t)n_out * (C_OUT / 4);
    size_t i = (size_t)blockIdx.x * 256 + threadIdx.x;
    const int c = (int)(i & 31) * 4;

    float4 sc, sh;
    {
        float m0 = stats[c + 0] * inv_n, m1 = stats[c + 1] * inv_n,
              m2 = stats[c + 2] * inv_n, m3 = stats[c + 3] * inv_n;
        float v0 = stats[C_OUT + c + 0] * inv_n - m0 * m0;
        float v1 = stats[C_OUT + c + 1] * inv_n - m1 * m1;
        float v2 = stats[C_OUT + c + 2] * inv_n - m2 * m2;
        float v3 = stats[C_OUT + c + 3] * inv_n - m3 * m3;
        sc.x = gamma[c + 0] * rsqrtf(v0 + BN_EPS);
        sc.y = gamma[c + 1] * rsqrtf(v1 + BN_EPS);
        sc.z = gamma[c + 2] * rsqrtf(v2 + BN_EPS);
        sc.w = gamma[c + 3] * rsqrtf(v3 + BN_EPS);
        sh.x = beta[c + 0] - m0 * sc.x;
        sh.y = beta[c + 1] - m1 * sc.y;
        sh.z = beta[c + 2] - m2 * sc.z;
        sh.w = beta[c + 3] - m3 * sc.w;
    }

    float4* o4 = (float4*)out;
    for (; i < total; i += (size_t)gridDim.x * 256) {
        float4 v = o4[i];
        v.x = v.x * sc.x + sh.x; v.x = v.x >= 0.f ? v.x : LEAK * v.x;
        v.y = v.y * sc.y + sh.y; v.y = v.y >= 0.f ? v.y : LEAK * v.y;
        v.z = v.z * sc.z + sh.z; v.z = v.z >= 0.f ? v.z : LEAK * v.z;
        v.w = v.w * sc.w + sh.w; v.w = v.w >= 0.f ? v.w : LEAK * v.w;
        o4[i] = v;
    }
}

// ---------------------------------------------------------------------------
extern "C" void kernel_launch(void* const* d_in, const int* in_sizes, int n_in,
                              void* d_out, int out_size, void* d_ws, size_t ws_size,
                              hipStream_t stream)
{
    const float* feats  = (const float*)d_in[0];
    const float* W      = (const float*)d_in[1];
    const float* gamma  = (const float*)d_in[2];
    const float* beta   = (const float*)d_in[3];
    const int*  in_idx  = (const int*)d_in[4];
    const int*  out_idx = (const int*)d_in[5];

    int P     = in_sizes[4] / KOFF;     // 262144
    int n_out = out_size / C_OUT;       // 262144

    dim3 grid_g(P / TILE_P, KOFF);      // 2048 x 4 (fallback path)

    const size_t half_bytes    = (size_t)n_out * C_OUT * sizeof(__half);   // 67 MB
    const size_t stats_bytes   = 2 * C_OUT * sizeof(float);                // 1 KB
    const size_t wt_off        = (half_bytes + stats_bytes + 255) & ~(size_t)255;
    const size_t wt_bytes      = (size_t)KOFF * C_OUT * C_IN * sizeof(unsigned short); // 64 KB
    const size_t partial_off   = wt_off + ((wt_bytes + 255) & ~(size_t)255);
    const size_t partial_bytes = (size_t)STATS_BLOCKS * 2 * C_OUT * sizeof(float);     // 2 MB
    const size_t partial2_off  = partial_off + partial_bytes;
    const size_t partial2_bytes = (size_t)8 * 2 * C_OUT * sizeof(float);   // 8 KB

    bool done = false;

    // ---------------- R8: single cooperative dispatch ----------------
    if (ws_size >= partial2_off + partial2_bytes) {
        static int coopG = -1;
        if (coopG < 0) {
            int maxb = 0;
            if (hipOccupancyMaxActiveBlocksPerMultiprocessor(
                    &maxb, fused_pipeline_kernel, 256, 0) == hipSuccess && maxb > 0) {
                hipDeviceProp_t prop;
                int dev = 0;
                hipGetDevice(&dev);
                if (hipGetDeviceProperties(&prop, dev) == hipSuccess)
                    coopG = maxb * prop.multiProcessorCount;
                else
                    coopG = 0;
            } else {
                coopG = 0;
            }
            if (coopG > STATS_BLOCKS) coopG = STATS_BLOCKS;   // partial buffer bound
            if (coopG < 8) coopG = 0;                         // need >=8 for reduce
        }

        if (coopG > 0) {
            __half2* outh = (__half2*)d_ws;
            unsigned short* Wt = (unsigned short*)((char*)d_ws + wt_off);
            float* partial  = (float*)((char*)d_ws + partial_off);
            float* partial2 = (float*)((char*)d_ws + partial2_off);
            float* outp = (float*)d_out;

            void* kargs[] = { (void*)&feats, (void*)&W, (void*)&in_idx, (void*)&out_idx,
                              (void*)&gamma, (void*)&beta, (void*)&outh, (void*)&Wt,
                              (void*)&partial, (void*)&partial2, (void*)&outp,
                              (void*)&P, (void*)&n_out };
            hipError_t e = hipLaunchCooperativeKernel(
                reinterpret_cast<void*>(fused_pipeline_kernel),
                dim3(coopG), dim3(256), kargs, 0, stream);
            if (e == hipSuccess) done = true;
        }
    }

    // ---------------- R7 multi-kernel fallback ----------------
    if (!done && ws_size >= partial_off + partial_bytes) {
        __half2* outh = (__half2*)d_ws;
        float* stats = (float*)((char*)d_ws + half_bytes);
        unsigned short* Wt = (unsigned short*)((char*)d_ws + wt_off);
        float* partial = (float*)((char*)d_ws + partial_off);

        const size_t fill_u4 = (half_bytes + stats_bytes) / 16;
        fill_wt_kernel<<<FILL_BLOCKS + KOFF, 256, 0, stream>>>(W, Wt, (uint4*)d_ws, fill_u4);

        scatter_gemm_mfma_kernel<<<grid_g, 256, 0, stream>>>(feats, Wt, in_idx, out_idx, outh, P);
        bn_stats_partial_kernel<<<STATS_BLOCKS, 256, 0, stream>>>(outh, partial, n_out);
        bn_reduce_kernel<<<8, 256, 0, stream>>>(partial, stats);
        bn_apply_half_kernel<<<2048, 256, 0, stream>>>(outh, (float*)d_out, stats,
                                                       gamma, beta, n_out, 1.0f / n_out);
        done = true;
    }

    // ---------------- fp32 last-resort fallback ----------------
    if (!done) {
        float* out   = (float*)d_out;
        float* stats = (float*)d_ws;
        hipMemsetAsync(d_out, 0, (size_t)out_size * sizeof(float), stream);
        hipMemsetAsync(d_ws, 0, 2 * C_OUT * sizeof(float), stream);

        scatter_gemm_f32_kernel<<<grid_g, 256, 0, stream>>>(feats, W, in_idx, out_idx, out, P);
        bn_stats_f32_kernel<<<1024, 256, 0, stream>>>(out, stats, n_out);
        bn_apply_f32_kernel<<<2048, 256, 0, stream>>>(out, stats, gamma, beta, n_out, 1.0f / n_out);
    }
}

// Round 6
// 990.382 us; speedup vs baseline: 1.0999x; 1.0999x over previous
//
#include <hip/hip_runtime.h>
#include <hip/hip_fp16.h>
#include <hip/hip_cooperative_groups.h>

// SparseConvolutionDownsample: rulebook sparse conv (gather -> GEMM -> scatter-add)
// + BatchNorm over active sites + LeakyReLU(0.333).
//
// Constants: C_IN=64, C_OUT=128, K=4, P=262144, n_out=262144.
//
// R9: R8's cooperative fusion, with the register clamp removed. R8 post-mortem:
// __launch_bounds__(256,8) forced 64 unified regs/wave -> VGPR_Count=32 ->
// conv phase lost its memory-level parallelism (atomics/gathers serialized at
// ~900cy each): 1258us with IDENTICAL MFMA/VALU cycle counts and exactly the
// predicted traffic -> pure stall. This round: __launch_bounds__(256) only,
// grid from the occupancy query (expect 4-5 blocks/CU, ~1280 blocks).
// Isolates "fusion at healthy occupancy" as the single variable.
// Fallbacks: R7 multi-kernel path if cooperative launch unavailable/fails;
// R2 fp32 path if ws tiny.

namespace cg = cooperative_groups;

#define C_IN   64
#define C_OUT  128
#define KOFF   4
#define TILE_P 128
#define SF_LD  72            // bf16 elems/row: 144B stride (16B-aligned)
#define BN_EPS 1e-4f
#define LEAK   0.333f
#define STATS_BLOCKS 2048    // stage-1 grid for partial stats (fallback path)
#define FILL_BLOCKS  4096    // zero-fill grid (fallback path)

typedef __attribute__((ext_vector_type(8)))  short short8;
typedef __attribute__((ext_vector_type(4)))  float f32x4;
typedef __attribute__((ext_vector_type(16))) float f32x16;

__device__ inline unsigned short f32_to_bf16_rn(float x) {
    unsigned int b = __float_as_uint(x);
    unsigned int r = (b + 0x7FFFu + ((b >> 16) & 1u)) >> 16;
    return (unsigned short)r;
}

struct h2pair { __half2 a, b; };   // 8 B = 4 channels

// ===========================================================================
// R9 fused cooperative pipeline.
// Phases: 0) zero accumulator + build Wt   1) conv (MFMA + pk_f16 scatter)
//         2) per-block partial stats       3) 8-block reduce -> partial2
//         4) BN apply + LeakyReLU
// LDS union across phases = 18.9 KB. NO min-occupancy clamp: conv needs
// ~100+ unified regs for atomic/gather pipelining (R8 lesson).
// ===========================================================================
__global__ __launch_bounds__(256) void fused_pipeline_kernel(
    const float* __restrict__ feats, const float* __restrict__ W,
    const int* __restrict__ in_idx, const int* __restrict__ out_idx,
    const float* __restrict__ gamma, const float* __restrict__ beta,
    __half2* __restrict__ outh, unsigned short* __restrict__ Wt,
    float* __restrict__ partial, float* __restrict__ partial2,
    float* __restrict__ outp, int P, int n_out)
{
    __shared__ union SMem {
        struct { unsigned short sF[TILE_P][SF_LD]; int sO[TILE_P]; } conv; // 18944 B
        struct { float4 red[256]; float4 red2[256]; } st;                  // 8192 B
        float sStats[2 * C_OUT];                                           // 1024 B
    } sm;

    cg::grid_group grid = cg::this_grid();
    const int tid = threadIdx.x;
    const int bid = blockIdx.x;
    const int G   = gridDim.x;

    // ---------------- Phase 0: zero accumulator; first KOFF blocks build Wt.
    {
        uint4* fill = (uint4*)outh;
        const size_t fill_u4 = ((size_t)n_out * C_OUT * 2) / 16;
        const uint4 z = make_uint4(0u, 0u, 0u, 0u);
        for (size_t i = (size_t)bid * 256 + tid; i < fill_u4; i += (size_t)G * 256)
            fill[i] = z;

        if (bid < KOFF) {
            const int k = bid;
            const int n  = tid >> 1;
            const int c0 = (tid & 1) * 32;
            unsigned int buf[16];
            #pragma unroll
            for (int j = 0; j < 16; ++j) {
                int cc = c0 + 2 * j;
                unsigned short lo = f32_to_bf16_rn(W[((size_t)k * C_IN + cc) * C_OUT + n]);
                unsigned short hh = f32_to_bf16_rn(W[((size_t)k * C_IN + cc + 1) * C_OUT + n]);
                buf[j] = (unsigned int)lo | ((unsigned int)hh << 16);
            }
            uint4* dst = (uint4*)(Wt + ((size_t)k * C_OUT + n) * C_IN + c0);
            dst[0] = make_uint4(buf[0],  buf[1],  buf[2],  buf[3]);
            dst[1] = make_uint4(buf[4],  buf[5],  buf[6],  buf[7]);
            dst[2] = make_uint4(buf[8],  buf[9],  buf[10], buf[11]);
            dst[3] = make_uint4(buf[12], buf[13], buf[14], buf[15]);
        }
    }
    grid.sync();

    // ---------------- Phase 1: conv (grid-stride over virtual tiles).
    {
        const int ntp = P / TILE_P;
        const int nvt = KOFF * ntp;
        const int l  = tid & 63;
        const int w  = tid >> 6;        // wave id -> col base 32w
        const int c  = l & 31;          // A row / B col / D col
        const int hi = l >> 5;          // k-half selector; D row +4*hi
        const bool odd = (c & 1) != 0;
        const int cpair = 16 * w + (c >> 1);

        for (int vt = bid; vt < nvt; vt += G) {
            const int k  = vt / ntp;
            const int p0 = (vt - k * ntp) * TILE_P;

            __syncthreads();   // protect LDS reuse across vt iterations
            if (tid < TILE_P)
                sm.conv.sO[tid] = out_idx[(size_t)k * P + p0 + tid];
            for (int i = tid; i < TILE_P * (C_IN / 4); i += 256) {
                int r  = i >> 4;
                int c4 = i & 15;
                int src = in_idx[(size_t)k * P + p0 + r];
                float4 v = ((const float4*)(feats + (size_t)src * C_IN))[c4];
                unsigned int lo = (unsigned int)f32_to_bf16_rn(v.x) | ((unsigned int)f32_to_bf16_rn(v.y) << 16);
                unsigned int hu = (unsigned int)f32_to_bf16_rn(v.z) | ((unsigned int)f32_to_bf16_rn(v.w) << 16);
                *(uint2*)&sm.conv.sF[r][c4 * 4] = make_uint2(lo, hu);
            }

            short8 bfr[4];
            {
                const unsigned short* wb = Wt + ((size_t)(k * C_OUT + 32 * w + c)) * C_IN + 8 * hi;
                #pragma unroll
                for (int s = 0; s < 4; ++s)
                    bfr[s] = *(const short8*)(wb + 16 * s);
            }
            __syncthreads();

            #pragma unroll
            for (int m = 0; m < 4; ++m) {
                f32x16 acc;
                #pragma unroll
                for (int j = 0; j < 16; ++j) acc[j] = 0.f;

                #pragma unroll
                for (int s = 0; s < 4; ++s) {
                    short8 a = *(const short8*)&sm.conv.sF[32 * m + c][16 * s + 8 * hi];
                    acc = __builtin_amdgcn_mfma_f32_32x32x16_bf16(a, bfr[s], acc, 0, 0, 0);
                }

                // Pair regs (e,e+1) -> rows (R,R+1); shfl_xor(1) pairs
                // adjacent-lane cols -> 4 distinct rows x full 64B per atomic.
                #pragma unroll
                for (int e = 0; e < 16; e += 2) {
                    const int rbase = 32 * m + (e & 3) + 8 * (e >> 2) + 4 * hi;
                    float va = acc[e], vb = acc[e + 1];
                    float ta = __shfl_xor(va, 1);
                    float tb = __shfl_xor(vb, 1);
                    int row = sm.conv.sO[rbase + (odd ? 1 : 0)];
                    __half2 h = odd ? __floats2half2_rn(tb, vb) : __floats2half2_rn(va, ta);
                    unsafeAtomicAdd(outh + (size_t)row * (C_OUT / 2) + cpair, h);
                }
            }
        }
    }
    grid.sync();

    // ---------------- Phase 2: per-block partial sum/sumsq (no atomics).
    {
        const int c4   = tid & 31;
        const int rgrp = tid >> 5;
        float4 s  = make_float4(0.f, 0.f, 0.f, 0.f);
        float4 s2 = make_float4(0.f, 0.f, 0.f, 0.f);
        for (int r = bid * 8 + rgrp; r < n_out; r += G * 8) {
            h2pair u = ((const h2pair*)(outh + (size_t)r * (C_OUT / 2)))[c4];
            float2 fa = __half22float2(u.a), fb = __half22float2(u.b);
            s.x += fa.x; s.y += fa.y; s.z += fb.x; s.w += fb.y;
            s2.x += fa.x * fa.x; s2.y += fa.y * fa.y; s2.z += fb.x * fb.x; s2.w += fb.y * fb.y;
        }
        sm.st.red[tid] = s; sm.st.red2[tid] = s2;
        __syncthreads();
        if (tid < 32) {
            #pragma unroll
            for (int j = 1; j < 8; ++j) {
                float4 a = sm.st.red[tid + 32 * j], b = sm.st.red2[tid + 32 * j];
                s.x += a.x; s.y += a.y; s.z += a.z; s.w += a.w;
                s2.x += b.x; s2.y += b.y; s2.z += b.z; s2.w += b.w;
            }
            float* pb = partial + (size_t)bid * 2 * C_OUT;
            ((float4*)pb)[tid] = s;
            ((float4*)(pb + C_OUT))[tid] = s2;
        }
    }
    grid.sync();

    // ---------------- Phase 3: reduce G partials -> partial2[8][256].
    if (bid < 8) {
        const int chunk = (G + 7) >> 3;
        const int b0 = bid * chunk;
        int b1 = b0 + chunk; if (b1 > G) b1 = G;
        float a = 0.f;
        for (int b = b0; b < b1; ++b)
            a += partial[(size_t)b * 2 * C_OUT + tid];
        partial2[(size_t)bid * 2 * C_OUT + tid] = a;
    }
    grid.sync();

    // ---------------- Phase 4: BN apply + LeakyReLU.
    {
        float a = 0.f;
        #pragma unroll
        for (int j = 0; j < 8; ++j)
            a += partial2[(size_t)j * 2 * C_OUT + tid];
        sm.sStats[tid] = a;
        __syncthreads();

        const float inv_n = 1.0f / (float)n_out;
        const size_t total = (size_t)n_out * (C_OUT / 4);
        size_t i = (size_t)bid * 256 + tid;
        const int c = (int)(tid & 31) * 4;

        float4 sc, sh;
        {
            float m0 = sm.sStats[c + 0] * inv_n, m1 = sm.sStats[c + 1] * inv_n,
                  m2 = sm.sStats[c + 2] * inv_n, m3 = sm.sStats[c + 3] * inv_n;
            float v0 = sm.sStats[C_OUT + c + 0] * inv_n - m0 * m0;
            float v1 = sm.sStats[C_OUT + c + 1] * inv_n - m1 * m1;
            float v2 = sm.sStats[C_OUT + c + 2] * inv_n - m2 * m2;
            float v3 = sm.sStats[C_OUT + c + 3] * inv_n - m3 * m3;
            sc.x = gamma[c + 0] * rsqrtf(v0 + BN_EPS);
            sc.y = gamma[c + 1] * rsqrtf(v1 + BN_EPS);
            sc.z = gamma[c + 2] * rsqrtf(v2 + BN_EPS);
            sc.w = gamma[c + 3] * rsqrtf(v3 + BN_EPS);
            sh.x = beta[c + 0] - m0 * sc.x;
            sh.y = beta[c + 1] - m1 * sc.y;
            sh.z = beta[c + 2] - m2 * sc.z;
            sh.w = beta[c + 3] - m3 * sc.w;
        }

        const h2pair* ih = (const h2pair*)outh;
        float4* o4 = (float4*)outp;
        for (; i < total; i += (size_t)G * 256) {
            h2pair u = ih[i];
            float2 fa = __half22float2(u.a), fb = __half22float2(u.b);
            float4 v = make_float4(fa.x, fa.y, fb.x, fb.y);
            v.x = v.x * sc.x + sh.x; v.x = v.x >= 0.f ? v.x : LEAK * v.x;
            v.y = v.y * sc.y + sh.y; v.y = v.y >= 0.f ? v.y : LEAK * v.y;
            v.z = v.z * sc.z + sh.z; v.z = v.z >= 0.f ? v.z : LEAK * v.z;
            v.w = v.w * sc.w + sh.w; v.w = v.w >= 0.f ? v.w : LEAK * v.w;
            o4[i] = v;
        }
    }
}

// ===========================================================================
// R7 MULTI-KERNEL FALLBACK PATH (unchanged)
// ===========================================================================

__global__ __launch_bounds__(256) void fill_wt_kernel(
    const float* __restrict__ W, unsigned short* __restrict__ Wt,
    uint4* __restrict__ fill, size_t fill_u4)
{
    const int bid = blockIdx.x;
    if (bid < FILL_BLOCKS) {
        const uint4 z = make_uint4(0u, 0u, 0u, 0u);
        size_t i = (size_t)bid * 256 + threadIdx.x;
        const size_t stride = (size_t)FILL_BLOCKS * 256;
        for (; i < fill_u4; i += stride)
            fill[i] = z;
        return;
    }

    const int k = bid - FILL_BLOCKS;
    const int t = threadIdx.x;
    const int n  = t >> 1;
    const int c0 = (t & 1) * 32;

    unsigned int buf[16];
    #pragma unroll
    for (int j = 0; j < 16; ++j) {
        int c = c0 + 2 * j;
        unsigned short lo = f32_to_bf16_rn(W[((size_t)k * C_IN + c) * C_OUT + n]);
        unsigned short hi = f32_to_bf16_rn(W[((size_t)k * C_IN + c + 1) * C_OUT + n]);
        buf[j] = (unsigned int)lo | ((unsigned int)hi << 16);
    }
    uint4* dst = (uint4*)(Wt + ((size_t)k * C_OUT + n) * C_IN + c0);
    dst[0] = make_uint4(buf[0],  buf[1],  buf[2],  buf[3]);
    dst[1] = make_uint4(buf[4],  buf[5],  buf[6],  buf[7]);
    dst[2] = make_uint4(buf[8],  buf[9],  buf[10], buf[11]);
    dst[3] = make_uint4(buf[12], buf[13], buf[14], buf[15]);
}

__global__ __launch_bounds__(256) void scatter_gemm_mfma_kernel(
    const float* __restrict__ feats, const unsigned short* __restrict__ Wt,
    const int* __restrict__ in_idx, const int* __restrict__ out_idx,
    __half2* __restrict__ outh, int P)
{
    __shared__ unsigned short sF[TILE_P][SF_LD];
    __shared__ int sO[TILE_P];

    const int tid = threadIdx.x;
    const int k  = blockIdx.y;
    const int p0 = blockIdx.x * TILE_P;

    if (tid < TILE_P)
        sO[tid] = out_idx[(size_t)k * P + p0 + tid];

    for (int i = tid; i < TILE_P * (C_IN / 4); i += 256) {
        int r  = i >> 4;
        int c4 = i & 15;
        int src = in_idx[(size_t)k * P + p0 + r];
        float4 v = ((const float4*)(feats + (size_t)src * C_IN))[c4];
        unsigned int lo = (unsigned int)f32_to_bf16_rn(v.x) | ((unsigned int)f32_to_bf16_rn(v.y) << 16);
        unsigned int hi = (unsigned int)f32_to_bf16_rn(v.z) | ((unsigned int)f32_to_bf16_rn(v.w) << 16);
        *(uint2*)&sF[r][c4 * 4] = make_uint2(lo, hi);
    }

    const int l  = tid & 63;
    const int w  = tid >> 6;
    const int c  = l & 31;
    const int hi = l >> 5;
    const bool odd = (c & 1) != 0;
    const int cpair = 16 * w + (c >> 1);

    short8 bfr[4];
    {
        const unsigned short* wb = Wt + ((size_t)(k * C_OUT + 32 * w + c)) * C_IN + 8 * hi;
        #pragma unroll
        for (int s = 0; s < 4; ++s)
            bfr[s] = *(const short8*)(wb + 16 * s);
    }

    __syncthreads();

    #pragma unroll
    for (int m = 0; m < 4; ++m) {
        f32x16 acc;
        #pragma unroll
        for (int j = 0; j < 16; ++j) acc[j] = 0.f;

        #pragma unroll
        for (int s = 0; s < 4; ++s) {
            short8 a = *(const short8*)&sF[32 * m + c][16 * s + 8 * hi];
            acc = __builtin_amdgcn_mfma_f32_32x32x16_bf16(a, bfr[s], acc, 0, 0, 0);
        }

        #pragma unroll
        for (int e = 0; e < 16; e += 2) {
            const int rbase = 32 * m + (e & 3) + 8 * (e >> 2) + 4 * hi;
            float va = acc[e], vb = acc[e + 1];
            float ta = __shfl_xor(va, 1);
            float tb = __shfl_xor(vb, 1);
            int row = sO[rbase + (odd ? 1 : 0)];
            __half2 h = odd ? __floats2half2_rn(tb, vb) : __floats2half2_rn(va, ta);
            unsafeAtomicAdd(outh + (size_t)row * (C_OUT / 2) + cpair, h);
        }
    }
}

__global__ __launch_bounds__(256) void bn_stats_partial_kernel(
    const __half2* __restrict__ outh, float* __restrict__ partial, int n_out)
{
    const int tid = threadIdx.x;
    const int c4   = tid & 31;
    const int rgrp = tid >> 5;

    float4 s  = make_float4(0.f, 0.f, 0.f, 0.f);
    float4 s2 = make_float4(0.f, 0.f, 0.f, 0.f);
    for (int r = blockIdx.x * 8 + rgrp; r < n_out; r += gridDim.x * 8) {
        h2pair u = ((const h2pair*)(outh + (size_t)r * (C_OUT / 2)))[c4];
        float2 fa = __half22float2(u.a), fb = __half22float2(u.b);
        s.x += fa.x; s.y += fa.y; s.z += fb.x; s.w += fb.y;
        s2.x += fa.x * fa.x; s2.y += fa.y * fa.y; s2.z += fb.x * fb.x; s2.w += fb.y * fb.y;
    }

    __shared__ float4 red[256], red2[256];
    red[tid] = s; red2[tid] = s2;
    __syncthreads();
    if (tid < 32) {
        #pragma unroll
        for (int j = 1; j < 8; ++j) {
            float4 a = red[tid + 32 * j], b = red2[tid + 32 * j];
            s.x += a.x; s.y += a.y; s.z += a.z; s.w += a.w;
            s2.x += b.x; s2.y += b.y; s2.z += b.z; s2.w += b.w;
        }
        float* pb = partial + (size_t)blockIdx.x * 2 * C_OUT;
        ((float4*)pb)[tid] = s;
        ((float4*)(pb + C_OUT))[tid] = s2;
    }
}

__global__ __launch_bounds__(256) void bn_reduce_kernel(
    const float* __restrict__ partial, float* __restrict__ stats)
{
    const int tid = threadIdx.x;
    const int b0 = blockIdx.x * (STATS_BLOCKS / 8);
    float a = 0.f;
    for (int b = b0; b < b0 + STATS_BLOCKS / 8; ++b)
        a += partial[(size_t)b * 2 * C_OUT + tid];
    atomicAdd(&stats[tid], a);
}

__global__ __launch_bounds__(256) void bn_apply_half_kernel(
    const __half2* __restrict__ outh, float* __restrict__ out,
    const float* __restrict__ stats,
    const float* __restrict__ gamma, const float* __restrict__ beta,
    int n_out, float inv_n)
{
    const size_t total = (size_t)n_out * (C_OUT / 4);
    size_t i = (size_t)blockIdx.x * 256 + threadIdx.x;
    const int c = (int)(i & 31) * 4;

    float4 sc, sh;
    {
        float m0 = stats[c + 0] * inv_n, m1 = stats[c + 1] * inv_n,
              m2 = stats[c + 2] * inv_n, m3 = stats[c + 3] * inv_n;
        float v0 = stats[C_OUT + c + 0] * inv_n - m0 * m0;
        float v1 = stats[C_OUT + c + 1] * inv_n - m1 * m1;
        float v2 = stats[C_OUT + c + 2] * inv_n - m2 * m2;
        float v3 = stats[C_OUT + c + 3] * inv_n - m3 * m3;
        sc.x = gamma[c + 0] * rsqrtf(v0 + BN_EPS);
        sc.y = gamma[c + 1] * rsqrtf(v1 + BN_EPS);
        sc.z = gamma[c + 2] * rsqrtf(v2 + BN_EPS);
        sc.w = gamma[c + 3] * rsqrtf(v3 + BN_EPS);
        sh.x = beta[c + 0] - m0 * sc.x;
        sh.y = beta[c + 1] - m1 * sc.y;
        sh.z = beta[c + 2] - m2 * sc.z;
        sh.w = beta[c + 3] - m3 * sc.w;
    }

    const h2pair* ih = (const h2pair*)outh;
    float4* o4 = (float4*)out;
    for (; i < total; i += (size_t)gridDim.x * 256) {
        h2pair u = ih[i];
        float2 fa = __half22float2(u.a), fb = __half22float2(u.b);
        float4 v = make_float4(fa.x, fa.y, fb.x, fb.y);
        v.x = v.x * sc.x + sh.x; v.x = v.x >= 0.f ? v.x : LEAK * v.x;
        v.y = v.y * sc.y + sh.y; v.y = v.y >= 0.f ? v.y : LEAK * v.y;
        v.z = v.z * sc.z + sh.z; v.z = v.z >= 0.f ? v.z : LEAK * v.z;
        v.w = v.w * sc.w + sh.w; v.w = v.w >= 0.f ? v.w : LEAK * v.w;
        o4[i] = v;
    }
}

// ===========================================================================
// FP32 FALLBACK PATH (R2, unchanged) — used if ws_size too small
// ===========================================================================

__global__ __launch_bounds__(256) void scatter_gemm_f32_kernel(
    const float* __restrict__ feats, const float* __restrict__ W,
    const int* __restrict__ in_idx, const int* __restrict__ out_idx,
    float* __restrict__ out, int P)
{
    __shared__ float sW[C_IN][C_OUT];
    __shared__ unsigned short sF[TILE_P][66];

    const int tid = threadIdx.x;
    const int k  = blockIdx.y;
    const int p0 = blockIdx.x * TILE_P;

    const float4* Wk4 = (const float4*)(W + (size_t)k * C_IN * C_OUT);
    float4* sW4 = (float4*)&sW[0][0];
    #pragma unroll
    for (int i = tid; i < C_IN * C_OUT / 4; i += 256)
        sW4[i] = Wk4[i];

    for (int i = tid; i < TILE_P * (C_IN / 4); i += 256) {
        int r  = i >> 4;
        int c4 = i & 15;
        int src = in_idx[(size_t)k * P + p0 + r];
        float4 v = ((const float4*)(feats + (size_t)src * C_IN))[c4];
        unsigned int lo = (unsigned int)f32_to_bf16_rn(v.x) | ((unsigned int)f32_to_bf16_rn(v.y) << 16);
        unsigned int hi = (unsigned int)f32_to_bf16_rn(v.z) | ((unsigned int)f32_to_bf16_rn(v.w) << 16);
        unsigned int* dst = (unsigned int*)&sF[r][c4 * 4];
        dst[0] = lo;
        dst[1] = hi;
    }
    __syncthreads();

    const int tx = tid & 15;
    const int ty = tid >> 4;

    float acc[8][8];
    #pragma unroll
    for (int r = 0; r < 8; ++r)
        #pragma unroll
        for (int j = 0; j < 8; ++j) acc[r][j] = 0.f;

    #pragma unroll 4
    for (int kk2 = 0; kk2 < C_IN / 2; ++kk2) {
        float w0[8], w1[8];
        #pragma unroll
        for (int j = 0; j < 8; ++j) {
            w0[j] = sW[2 * kk2 + 0][tx + 16 * j];
            w1[j] = sW[2 * kk2 + 1][tx + 16 * j];
        }
        float f0[8], f1[8];
        #pragma unroll
        for (int r = 0; r < 8; ++r) {
            unsigned int u = *(const unsigned int*)&sF[8 * ty + r][2 * kk2];
            f0[r] = __uint_as_float(u << 16);
            f1[r] = __uint_as_float(u & 0xFFFF0000u);
        }
        #pragma unroll
        for (int r = 0; r < 8; ++r)
            #pragma unroll
            for (int j = 0; j < 8; ++j) {
                acc[r][j] = fmaf(f0[r], w0[j], acc[r][j]);
                acc[r][j] = fmaf(f1[r], w1[j], acc[r][j]);
            }
    }

    #pragma unroll
    for (int r = 0; r < 8; ++r) {
        int orow = out_idx[(size_t)k * P + p0 + 8 * ty + r];
        float* op = out + (size_t)orow * C_OUT + tx;
        #pragma unroll
        for (int j = 0; j < 8; ++j)
            atomicAdd(op + 16 * j, acc[r][j]);
    }
}

__global__ __launch_bounds__(256) void bn_stats_f32_kernel(
    const float* __restrict__ out, float* __restrict__ stats, int n_out)
{
    const int tid = threadIdx.x;
    const int c4   = tid & 31;
    const int rgrp = tid >> 5;

    float4 s  = make_float4(0.f, 0.f, 0.f, 0.f);
    float4 s2 = make_float4(0.f, 0.f, 0.f, 0.f);
    for (int r = blockIdx.x * 8 + rgrp; r < n_out; r += gridDim.x * 8) {
        float4 v = ((const float4*)(out + (size_t)r * C_OUT))[c4];
        s.x += v.x; s.y += v.y; s.z += v.z; s.w += v.w;
        s2.x += v.x * v.x; s2.y += v.y * v.y; s2.z += v.z * v.z; s2.w += v.w * v.w;
    }

    __shared__ float4 red[256], red2[256];
    red[tid] = s; red2[tid] = s2;
    __syncthreads();
    if (tid < 32) {
        #pragma unroll
        for (int j = 1; j < 8; ++j) {
            float4 a = red[tid + 32 * j], b = red2[tid + 32 * j];
            s.x += a.x; s.y += a.y; s.z += a.z; s.w += a.w;
            s2.x += b.x; s2.y += b.y; s2.z += b.z; s2.w += b.w;
        }
        atomicAdd(&stats[4 * tid + 0], s.x);
        atomicAdd(&stats[4 * tid + 1], s.y);
        atomicAdd(&stats[4 * tid + 2], s.z);
        atomicAdd(&stats[4 * tid + 3], s.w);
        atomicAdd(&stats[C_OUT + 4 * tid + 0], s2.x);
        atomicAdd(&stats[C_OUT + 4 * tid + 1], s2.y);
        atomicAdd(&stats[C_OUT + 4 * tid + 2], s2.z);
        atomicAdd(&stats[C_OUT + 4 * tid + 3], s2.w);
    }
}

__global__ __launch_bounds__(256) void bn_apply_f32_kernel(
    float* __restrict__ out, const float* __restrict__ stats,
    const float* __restrict__ gamma, const float* __restrict__ beta,
    int n_out, float inv_n)
{
    const size_t total = (size_t)n_out * (C_OUT / 4);
    size_t i = (size_t)blockIdx.x * 256 + threadIdx.x;
    const int c = (int)(i & 31) * 4;

    float4 sc, sh;
    {
        float m0 = stats[c + 0] * inv_n, m1 = stats[c + 1] * inv_n,
              m2 = stats[c + 2] * inv_n, m3 = stats[c + 3] * inv_n;
        float v0 = stats[C_OUT + c + 0] * inv_n - m0 * m0;
        float v1 = stats[C_OUT + c + 1] * inv_n - m1 * m1;
        float v2 = stats[C_OUT + c + 2] * inv_n - m2 * m2;
        float v3 = stats[C_OUT + c + 3] * inv_n - m3 * m3;
        sc.x = gamma[c + 0] * rsqrtf(v0 + BN_EPS);
        sc.y = gamma[c + 1] * rsqrtf(v1 + BN_EPS);
        sc.z = gamma[c + 2] * rsqrtf(v2 + BN_EPS);
        sc.w = gamma[c + 3] * rsqrtf(v3 + BN_EPS);
        sh.x = beta[c + 0] - m0 * sc.x;
        sh.y = beta[c + 1] - m1 * sc.y;
        sh.z = beta[c + 2] - m2 * sc.z;
        sh.w = beta[c + 3] - m3 * sc.w;
    }

    float4* o4 = (float4*)out;
    for (; i < total; i += (size_t)gridDim.x * 256) {
        float4 v = o4[i];
        v.x = v.x * sc.x + sh.x; v.x = v.x >= 0.f ? v.x : LEAK * v.x;
        v.y = v.y * sc.y + sh.y; v.y = v.y >= 0.f ? v.y : LEAK * v.y;
        v.z = v.z * sc.z + sh.z; v.z = v.z >= 0.f ? v.z : LEAK * v.z;
        v.w = v.w * sc.w + sh.w; v.w = v.w >= 0.f ? v.w : LEAK * v.w;
        o4[i] = v;
    }
}

// ---------------------------------------------------------------------------
extern "C" void kernel_launch(void* const* d_in, const int* in_sizes, int n_in,
                              void* d_out, int out_size, void* d_ws, size_t ws_size,
                              hipStream_t stream)
{
    const float* feats  = (const float*)d_in[0];
    const float* W      = (const float*)d_in[1];
    const float* gamma  = (const float*)d_in[2];
    const float* beta   = (const float*)d_in[3];
    const int*  in_idx  = (const int*)d_in[4];
    const int*  out_idx = (const int*)d_in[5];

    int P     = in_sizes[4] / KOFF;     // 262144
    int n_out = out_size / C_OUT;       // 262144

    dim3 grid_g(P / TILE_P, KOFF);      // 2048 x 4 (fallback path)

    const size_t half_bytes    = (size_t)n_out * C_OUT * sizeof(__half);   // 67 MB
    const size_t stats_bytes   = 2 * C_OUT * sizeof(float);                // 1 KB
    const size_t wt_off        = (half_bytes + stats_bytes + 255) & ~(size_t)255;
    const size_t wt_bytes      = (size_t)KOFF * C_OUT * C_IN * sizeof(unsigned short); // 64 KB
    const size_t partial_off   = wt_off + ((wt_bytes + 255) & ~(size_t)255);
    const size_t partial_bytes = (size_t)STATS_BLOCKS * 2 * C_OUT * sizeof(float);     // 2 MB
    const size_t partial2_off  = partial_off + partial_bytes;
    const size_t partial2_bytes = (size_t)8 * 2 * C_OUT * sizeof(float);   // 8 KB

    bool done = false;

    // ---------------- R9: single cooperative dispatch ----------------
    if (ws_size >= partial2_off + partial2_bytes) {
        static int coopG = -1;
        if (coopG < 0) {
            int maxb = 0;
            if (hipOccupancyMaxActiveBlocksPerMultiprocessor(
                    &maxb, fused_pipeline_kernel, 256, 0) == hipSuccess && maxb > 0) {
                hipDeviceProp_t prop;
                int dev = 0;
                hipGetDevice(&dev);
                if (hipGetDeviceProperties(&prop, dev) == hipSuccess)
                    coopG = maxb * prop.multiProcessorCount;
                else
                    coopG = 0;
            } else {
                coopG = 0;
            }
            if (coopG > STATS_BLOCKS) coopG = STATS_BLOCKS;   // partial buffer bound
            if (coopG < 8) coopG = 0;                         // need >=8 for reduce
        }

        if (coopG > 0) {
            __half2* outh = (__half2*)d_ws;
            unsigned short* Wt = (unsigned short*)((char*)d_ws + wt_off);
            float* partial  = (float*)((char*)d_ws + partial_off);
            float* partial2 = (float*)((char*)d_ws + partial2_off);
            float* outp = (float*)d_out;

            void* kargs[] = { (void*)&feats, (void*)&W, (void*)&in_idx, (void*)&out_idx,
                              (void*)&gamma, (void*)&beta, (void*)&outh, (void*)&Wt,
                              (void*)&partial, (void*)&partial2, (void*)&outp,
                              (void*)&P, (void*)&n_out };
            hipError_t e = hipLaunchCooperativeKernel(
                reinterpret_cast<void*>(fused_pipeline_kernel),
                dim3(coopG), dim3(256), kargs, 0, stream);
            if (e == hipSuccess) done = true;
        }
    }

    // ---------------- R7 multi-kernel fallback ----------------
    if (!done && ws_size >= partial_off + partial_bytes) {
        __half2* outh = (__half2*)d_ws;
        float* stats = (float*)((char*)d_ws + half_bytes);
        unsigned short* Wt = (unsigned short*)((char*)d_ws + wt_off);
        float* partial = (float*)((char*)d_ws + partial_off);

        const size_t fill_u4 = (half_bytes + stats_bytes) / 16;
        fill_wt_kernel<<<FILL_BLOCKS + KOFF, 256, 0, stream>>>(W, Wt, (uint4*)d_ws, fill_u4);

        scatter_gemm_mfma_kernel<<<grid_g, 256, 0, stream>>>(feats, Wt, in_idx, out_idx, outh, P);
        bn_stats_partial_kernel<<<STATS_BLOCKS, 256, 0, stream>>>(outh, partial, n_out);
        bn_reduce_kernel<<<8, 256, 0, stream>>>(partial, stats);
        bn_apply_half_kernel<<<2048, 256, 0, stream>>>(outh, (float*)d_out, stats,
                                                       gamma, beta, n_out, 1.0f / n_out);
        done = true;
    }

    // ---------------- fp32 last-resort fallback ----------------
    if (!done) {
        float* out   = (float*)d_out;
        float* stats = (float*)d_ws;
        hipMemsetAsync(d_out, 0, (size_t)out_size * sizeof(float), stream);
        hipMemsetAsync(d_ws, 0, 2 * C_OUT * sizeof(float), stream);

        scatter_gemm_f32_kernel<<<grid_g, 256, 0, stream>>>(feats, W, in_idx, out_idx, out, P);
        bn_stats_f32_kernel<<<1024, 256, 0, stream>>>(out, stats, n_out);
        bn_apply_f32_kernel<<<2048, 256, 0, stream>>>(out, stats, gamma, beta, n_out, 1.0f / n_out);
    }
}